// Round 2
// baseline (175.299 us; speedup 1.0000x reference)
//
#include <hip/hip_runtime.h>

// MetaBaseline: B,Q,WAY,SHOT,H,W,C = 2,75,5,5,10,10,640; k=5
#define QN    75
#define HWN   100
#define CN    640
#define NSUP  500                      // support descriptors per (b, group)
#define MROWS 7500                     // query patches per batch
#define NQD   (2 * MROWS)              // 15000
#define NSD   5000
#define NDESC (NQD + NSD)              // 20000
#define MT    128                      // rows per workgroup
#define NT    256                      // cols per workgroup (split-N: 2 chunks)
#define BK    64                       // K-chunk (10 iterations)
#define CST   272                      // epilogue C stride (dwords); 272%32==16 -> 2-way scan
#define BUFSZ 49152                    // one LDS buffer: A 16 KB + B 32 KB

typedef __attribute__((ext_vector_type(8))) __bf16 bf16x8;
typedef __attribute__((ext_vector_type(4))) float  f32x4;

// async global->LDS DMA, 16B per lane; LDS dest = wave-uniform base + lane*16
#define GLDS(gp, lp) __builtin_amdgcn_global_load_lds(                        \
    (const __attribute__((address_space(1))) void*)(gp),                      \
    (__attribute__((address_space(3))) void*)(lp), 16, 0, 0)

static __device__ inline unsigned short f2bf(float f) {
    unsigned int u = __float_as_uint(f);
    u += 0x7fffu + ((u >> 16) & 1u);        // RNE
    return (unsigned short)(u >> 16);
}

// ---------------------------------------------------------------------------
// Prep (fused, R6 version): one wave per descriptor, inv-norm, write
// normalized bf16 to ws.
// ---------------------------------------------------------------------------
__global__ __launch_bounds__(256) void prep_kernel(const float* __restrict__ q,
                                                   const float* __restrict__ s,
                                                   unsigned short* __restrict__ qbf,
                                                   unsigned short* __restrict__ sbf) {
    int wave = (blockIdx.x * 256 + threadIdx.x) >> 6;
    int lane = threadIdx.x & 63;
    if (wave >= NDESC) return;
    const float* src = (wave < NQD) ? (q + (size_t)wave * CN)
                                    : (s + (size_t)(wave - NQD) * CN);
    unsigned short* dst = (wave < NQD) ? (qbf + (size_t)wave * CN)
                                       : (sbf + (size_t)(wave - NQD) * CN);
    float4 v[3];
    float ss = 0.f;
#pragma unroll
    for (int j = 0; j < 3; ++j) {
        int idx4 = lane + 64 * j;
        if (idx4 < CN / 4) {
            v[j] = *(const float4*)(src + idx4 * 4);
            ss = fmaf(v[j].x, v[j].x, ss);
            ss = fmaf(v[j].y, v[j].y, ss);
            ss = fmaf(v[j].z, v[j].z, ss);
            ss = fmaf(v[j].w, v[j].w, ss);
        }
    }
#pragma unroll
    for (int off = 32; off > 0; off >>= 1)
        ss += __shfl_xor(ss, off, 64);
    float inv = rsqrtf(ss);
#pragma unroll
    for (int j = 0; j < 3; ++j) {
        int idx4 = lane + 64 * j;
        if (idx4 < CN / 4) {
            ushort4 o;
            o.x = f2bf(v[j].x * inv);
            o.y = f2bf(v[j].y * inv);
            o.z = f2bf(v[j].z * inv);
            o.w = f2bf(v[j].w * inv);
            *(ushort4*)(dst + idx4 * 4) = o;
        }
    }
}

// ---------------------------------------------------------------------------
// MFMA GEMM (128x256 tile, 512 threads = 8 waves) + per-row top-5 partials.
// R11: XCD-clustered work remap (kept).
// R13: counted-vmcnt double-buffer (T4). R12's dbuf regressed because
// __syncthreads emits s_waitcnt vmcnt(0) -- it drained the JUST-ISSUED
// prefetch, so the pipeline never formed (and 96 KB LDS halved occupancy
// for nothing). Fix: raw s_barrier + counted s_waitcnt vmcnt(6): each wave
// waits only for its tile-t loads (6 of them), leaving tile t+1's 6 in
// flight through COMPUTE. Per-wave vmcnt + s_barrier = collective wait.
// lgkmcnt(0) before the trailing barrier: no wave may pass with in-flight
// ds_reads from the buffer the next iteration's DMA overwrites (rule 18:
// sched_barrier(0) after every inline waitcnt).
// Epilogue Cst (34.8 KB) aliases buf0 only; final K-step reads buf1.
// ---------------------------------------------------------------------------
__global__ __launch_bounds__(512, 2) void mfma_kernel(const unsigned short* __restrict__ qbf,
                                                      const unsigned short* __restrict__ sbf,
                                                      float* __restrict__ part) {
    // ---- work decode: grid = 1200 1-D blocks ----
    const int xcd = blockIdx.x & 7;
    const int idx = blockIdx.x >> 3;          // 0..149
    const int b   = xcd >> 2;                 // batch (0/1)
    const int mbq = xcd & 3;                  // M quarter
    const int mbsz = (mbq < 3) ? 15 : 14;     // quarter sizes: 15,15,15,14 (=59)
    if (idx >= 10 * mbsz) return;             // block-uniform early exit
    const int g  = idx / (2 * mbsz);
    const int r_ = idx % (2 * mbsz);
    const int nc = r_ / mbsz;
    const int mb = mbq * 15 + (r_ % mbsz);    // 0..58
    const int bg = b * 5 + g;
    const int r0 = mb * MT;
    const int c0 = nc * NT;

    __shared__ __align__(16) char smem[2 * BUFSZ];         // double-buffered A+B
    float* Cst = (float*)smem;                             // epilogue [32][CST] = 34.8 KB (buf0)

    const int t    = threadIdx.x;
    const int lane = t & 63;
    const int wid  = t >> 6;               // 0..7
    const int h    = wid >> 2;             // row half (0/1)
    const int colq = wid & 3;              // col quarter (0..3)

    const unsigned short* qptr = qbf + (size_t)b * MROWS * CN;              // uniform
    const unsigned short* sptr = sbf + (size_t)(b * 25 + g * 5) * HWN * CN; // uniform

    f32x4 acc[4][4];
#pragma unroll
    for (int mt = 0; mt < 4; ++mt)
#pragma unroll
        for (int nt = 0; nt < 4; ++nt)
            acc[mt][nt] = (f32x4)0.f;

    // ---- async staging setup (per-lane source offset, uniform LDS dest) ----
    const int lx   = lane >> 3;          // 0..7: row/col within 8-row chunk
    const int ls   = lane & 7;           // dest slot (lane-fixed)
    const int gsrc = ls ^ lx;            // source granule for this lane

    // A: wave w stages rows [w*16, +16) as 2 chunks of 8 rows
    int ar0 = r0 + wid * 16 + lx;       if (ar0 > MROWS - 1) ar0 = MROWS - 1;
    int ar1 = r0 + wid * 16 + 8 + lx;   if (ar1 > MROWS - 1) ar1 = MROWS - 1;
    const int aoff0 = ar0 * CN + gsrc * 8;
    const int aoff1 = ar1 * CN + gsrc * 8;

    // B: wave w stages cols [c0 + w*32, +32) as 4 chunks of 8 cols (clamped)
    int boff[4];
#pragma unroll
    for (int c = 0; c < 4; ++c) {
        int col = c0 + wid * 32 + c * 8 + lx;
        if (col > NSUP - 1) col = NSUP - 1;
        boff[c] = col * CN + gsrc * 8;
    }

    const int q_ = lane >> 4;      // k-quad
    const int lr = lane & 15;      // row/col within 16x16 tile
    const int sw = lr & 7;         // read-side swizzle term

    // stage one 48 KB tile (A 16 KB + B 32 KB) at k-offset kk into buffer base
#define STAGE(base, kk)                                                        \
    {                                                                          \
        char* ad = smem + (base) + wid * 2048;                                 \
        char* bd = smem + (base) + 16384 + wid * 4096;                         \
        GLDS(qptr + aoff0 + (kk), ad);                                         \
        GLDS(qptr + aoff1 + (kk), ad + 1024);                                  \
        GLDS(sptr + boff[0] + (kk), bd);                                       \
        GLDS(sptr + boff[1] + (kk), bd + 1024);                                \
        GLDS(sptr + boff[2] + (kk), bd + 2048);                                \
        GLDS(sptr + boff[3] + (kk), bd + 3072);                                \
    }

    // consume one buffered tile: 16 ds_read_b128 + 32 MFMA per wave
#define COMPUTE(base)                                                          \
    {                                                                          \
        const unsigned short* Al = (const unsigned short*)(smem + (base));     \
        const unsigned short* Bl = (const unsigned short*)(smem + (base) + 16384); \
        _Pragma("unroll")                                                      \
        for (int ks = 0; ks < 2; ++ks) {                                       \
            const int sl = ((ks * 4 + q_) ^ sw) * 8;                           \
            bf16x8 af[4];                                                      \
            _Pragma("unroll")                                                  \
            for (int mt = 0; mt < 4; ++mt)                                     \
                af[mt] = *(const bf16x8*)(Al + (h * 64 + mt * 16 + lr) * 64 + sl); \
            _Pragma("unroll")                                                  \
            for (int nt = 0; nt < 4; ++nt) {                                   \
                bf16x8 bfr = *(const bf16x8*)(Bl + (colq * 64 + nt * 16 + lr) * 64 + sl); \
                _Pragma("unroll")                                              \
                for (int mt = 0; mt < 4; ++mt)                                 \
                    acc[mt][nt] = __builtin_amdgcn_mfma_f32_16x16x32_bf16(af[mt], bfr, acc[mt][nt], 0, 0, 0); \
            }                                                                  \
        }                                                                      \
    }

    // ---- pipelined main loop: counted vmcnt keeps prefetch in flight ----
    STAGE(0, 0);                              // tile 0 -> buf0 (6 loads in flight)
#pragma unroll
    for (int kt = 0; kt < 9; ++kt) {
        const int cb = (kt & 1) * BUFSZ;      // current buffer
        STAGE(BUFSZ - cb, (kt + 1) * BK);     // tile kt+1 -> other buf (12 in flight)
        asm volatile("s_waitcnt vmcnt(6)" ::: "memory");   // tile kt landed (own 6)
        __builtin_amdgcn_sched_barrier(0);
        __builtin_amdgcn_s_barrier();                      // collective: all 48 landed
        COMPUTE(cb);                          // MFMA under tile kt+1's DMA flight
        asm volatile("s_waitcnt lgkmcnt(0)" ::: "memory"); // my ds_reads of cb done
        __builtin_amdgcn_sched_barrier(0);
        __builtin_amdgcn_s_barrier();         // nobody still reading buf^1 next iter
    }
    asm volatile("s_waitcnt vmcnt(0)" ::: "memory");       // tile 9 landed
    __builtin_amdgcn_sched_barrier(0);
    __builtin_amdgcn_s_barrier();
    COMPUTE(BUFSZ);                           // tile 9 (buf1; Cst aliases buf0 only)
#undef STAGE
#undef COMPUTE

    // -------- epilogue: per-mt, 32 C-rows (both halves) via LDS -----------
    // FULLY UNROLLED over mt (runtime acc[] index -> scratch spill; see R2).
    const int erow = t >> 4;        // 0..31 (Cst row)
    const int es   = t & 15;        // 16 scanners per row (within one wave)
#define CE(a, b) { float hi_ = fmaxf(a, b), lo_ = fminf(a, b); a = hi_; b = lo_; }
#pragma unroll
    for (int mt = 0; mt < 4; ++mt) {
        __syncthreads();
#pragma unroll
        for (int nt = 0; nt < 4; ++nt)
#pragma unroll
            for (int e = 0; e < 4; ++e)
                Cst[(h * 16 + q_ * 4 + e) * CST + colq * 64 + nt * 16 + lr] = acc[mt][nt][e];
        __syncthreads();

        float t0 = -3.4e38f, t1 = -3.4e38f, t2 = -3.4e38f, t3 = -3.4e38f, t4 = -3.4e38f;
#pragma unroll
        for (int i = 0; i < 16; ++i) {
            int col = es + 16 * i;
            float v = (c0 + col < NSUP) ? Cst[erow * CST + col] : -3.4e38f;
            float hi;
            hi = fmaxf(t0, v); v = fminf(t0, v); t0 = hi;
            hi = fmaxf(t1, v); v = fminf(t1, v); t1 = hi;
            hi = fmaxf(t2, v); v = fminf(t2, v); t2 = hi;
            hi = fmaxf(t3, v); v = fminf(t3, v); t3 = hi;
            hi = fmaxf(t4, v); v = fminf(t4, v); t4 = hi;
        }
#pragma unroll
        for (int d = 1; d < 16; d <<= 1) {
            float b0 = __shfl_xor(t0, d, 64);
            float b1 = __shfl_xor(t1, d, 64);
            float b2 = __shfl_xor(t2, d, 64);
            float b3 = __shfl_xor(t3, d, 64);
            float b4 = __shfl_xor(t4, d, 64);
            t0 = fmaxf(t0, b4); t1 = fmaxf(t1, b3); t2 = fmaxf(t2, b2);
            t3 = fmaxf(t3, b1); t4 = fmaxf(t4, b0);
            CE(t0, t1); CE(t2, t3);
            CE(t1, t2); CE(t3, t4);
            CE(t0, t1); CE(t2, t3);
            CE(t1, t2); CE(t3, t4);
            CE(t0, t1); CE(t2, t3);
        }
        if (es == 0) {
            // Cst row erow = eh*16 + crow maps to patch r0 + eh*64 + mt*16 + crow
            int patch = r0 + (erow >> 4) * 64 + mt * 16 + (erow & 15);
            if (patch < MROWS) {
                float* pp = part + ((size_t)(bg * MROWS + patch) * 2 + nc) * 5;
                pp[0] = t0; pp[1] = t1; pp[2] = t2; pp[3] = t3; pp[4] = t4;
            }
        }
    }
#undef CE
}

// ---------------------------------------------------------------------------
// Merge: one wave per (b,qi,g) = 750 waves. Top-5 of the union of the two
// sorted per-chunk top-5s, mean, wave-reduce over 100 patches, direct store.
// ---------------------------------------------------------------------------
__global__ __launch_bounds__(256) void merge_kernel(const float* __restrict__ part,
                                                    float* __restrict__ out) {
    int w    = (blockIdx.x * 256 + threadIdx.x) >> 6;
    int lane = threadIdx.x & 63;
    if (w >= 750) return;
    int b  = w / 375, r = w % 375;
    int qi = r / 5,   g = r % 5;
    int bg = b * 5 + g;

    float sum = 0.f;
    for (int p = lane; p < HWN; p += 64) {
        int row = qi * HWN + p;
        const float* pp = part + (size_t)(bg * MROWS + row) * 10;
        float t0 = -3.4e38f, t1 = -3.4e38f, t2 = -3.4e38f, t3 = -3.4e38f, t4 = -3.4e38f;
#pragma unroll
        for (int j = 0; j < 10; ++j) {
            float v = pp[j], hi;
            hi = fmaxf(t0, v); v = fminf(t0, v); t0 = hi;
            hi = fmaxf(t1, v); v = fminf(t1, v); t1 = hi;
            hi = fmaxf(t2, v); v = fminf(t2, v); t2 = hi;
            hi = fmaxf(t3, v); v = fminf(t3, v); t3 = hi;
            hi = fmaxf(t4, v); v = fminf(t4, v); t4 = hi;
        }
        sum += (t0 + t1 + t2 + t3 + t4) * 0.2f;
    }
#pragma unroll
    for (int off = 32; off > 0; off >>= 1)
        sum += __shfl_xor(sum, off, 64);
    if (lane == 0) out[w] = sum;        // out[(b*75+qi)*5+g] == out[w]
}

extern "C" void kernel_launch(void* const* d_in, const int* in_sizes, int n_in,
                              void* d_out, int out_size, void* d_ws, size_t ws_size,
                              hipStream_t stream) {
    const float* in1 = (const float*)d_in[0];
    const float* in2 = (const float*)d_in[1];
    float* out = (float*)d_out;

    unsigned short* qbf  = (unsigned short*)d_ws;            // 15000*640 bf16 = 19.2 MB
    unsigned short* sbf  = qbf + (size_t)NQD * CN;           //  5000*640 bf16 =  6.4 MB
    float*          part = (float*)(sbf + (size_t)NSD * CN); // 750000 fp32 = 3 MB

    prep_kernel<<<dim3(NDESC / 4), 256, 0, stream>>>(in1, in2, qbf, sbf);
    mfma_kernel<<<dim3(1200), 512, 0, stream>>>(qbf, sbf, part);   // XCD-clustered
    merge_kernel<<<dim3(188), 256, 0, stream>>>(part, out);        // 750 waves
}

// Round 3
// 163.789 us; speedup vs baseline: 1.0703x; 1.0703x over previous
//
#include <hip/hip_runtime.h>

// MetaBaseline: B,Q,WAY,SHOT,H,W,C = 2,75,5,5,10,10,640; k=5
#define QN    75
#define HWN   100
#define CN    640
#define NSUP  500                      // support descriptors per (b, group)
#define MROWS 7500                     // query patches per batch
#define NQD   (2 * MROWS)              // 15000
#define NSD   5000
#define NDESC (NQD + NSD)              // 20000
#define MT    128                      // rows per workgroup
#define NT    256                      // cols per workgroup (split-N: 2 chunks)
#define BK    32                       // K-chunk (20 tiles) -- R14: halved for in-place dbuf
#define HBUF  24576                    // half-buffer: A 8 KB + B 16 KB
#define CST   272                      // epilogue C stride (dwords); 272%32==16 -> 2-way scan

typedef __attribute__((ext_vector_type(8))) __bf16 bf16x8;
typedef __attribute__((ext_vector_type(4))) float  f32x4;

// async global->LDS DMA, 16B per lane; LDS dest = wave-uniform base + lane*16
#define GLDS(gp, lp) __builtin_amdgcn_global_load_lds(                        \
    (const __attribute__((address_space(1))) void*)(gp),                      \
    (__attribute__((address_space(3))) void*)(lp), 16, 0, 0)

static __device__ inline unsigned short f2bf(float f) {
    unsigned int u = __float_as_uint(f);
    u += 0x7fffu + ((u >> 16) & 1u);        // RNE
    return (unsigned short)(u >> 16);
}

// ---------------------------------------------------------------------------
// Prep (fused, R6 version): one wave per descriptor, inv-norm, write
// normalized bf16 to ws.
// ---------------------------------------------------------------------------
__global__ __launch_bounds__(256) void prep_kernel(const float* __restrict__ q,
                                                   const float* __restrict__ s,
                                                   unsigned short* __restrict__ qbf,
                                                   unsigned short* __restrict__ sbf) {
    int wave = (blockIdx.x * 256 + threadIdx.x) >> 6;
    int lane = threadIdx.x & 63;
    if (wave >= NDESC) return;
    const float* src = (wave < NQD) ? (q + (size_t)wave * CN)
                                    : (s + (size_t)(wave - NQD) * CN);
    unsigned short* dst = (wave < NQD) ? (qbf + (size_t)wave * CN)
                                       : (sbf + (size_t)(wave - NQD) * CN);
    float4 v[3];
    float ss = 0.f;
#pragma unroll
    for (int j = 0; j < 3; ++j) {
        int idx4 = lane + 64 * j;
        if (idx4 < CN / 4) {
            v[j] = *(const float4*)(src + idx4 * 4);
            ss = fmaf(v[j].x, v[j].x, ss);
            ss = fmaf(v[j].y, v[j].y, ss);
            ss = fmaf(v[j].z, v[j].z, ss);
            ss = fmaf(v[j].w, v[j].w, ss);
        }
    }
#pragma unroll
    for (int off = 32; off > 0; off >>= 1)
        ss += __shfl_xor(ss, off, 64);
    float inv = rsqrtf(ss);
#pragma unroll
    for (int j = 0; j < 3; ++j) {
        int idx4 = lane + 64 * j;
        if (idx4 < CN / 4) {
            ushort4 o;
            o.x = f2bf(v[j].x * inv);
            o.y = f2bf(v[j].y * inv);
            o.z = f2bf(v[j].z * inv);
            o.w = f2bf(v[j].w * inv);
            *(ushort4*)(dst + idx4 * 4) = o;
        }
    }
}

// ---------------------------------------------------------------------------
// MFMA GEMM (128x256 tile, 512 threads = 8 waves) + per-row top-5 partials.
// R11: XCD-clustered work remap (kept).
// R14: in-place double-buffer at BK=32. Post-mortem matrix:
//   R11 (2 blk/CU, no intra overlap)       75.3 us
//   R12 (1 blk/CU, intra overlap)          86.9 us  <- 96KB LDS killed occupancy
//   R13 (1 blk/CU, overlap + barrier pins) 91.2 us
// Missing cell: 2 blk/CU AND intra-block overlap. Achieved by halving the
// K-grain: two 24KB buffers fit the ORIGINAL 48KB footprint. Per step each
// wave stages 3 GLDS for tile t+1, computes tile t (4+4 ds_read_b128,
// 16 MFMA), then one __syncthreads() whose vmcnt(0) drains a prefetch that
// flew under this step's compute. Occupancy, DMA count, barrier count all
// unchanged vs R11 -- the only delta is per-step DMA+compute -> max(DMA,
// compute). 32-wide rows have 4 granules: swizzle g ^ ((row^(row>>2))&3)
// (plain row&3 would 4-way-conflict rows lr,lr+4,lr+8,lr+12 per quarter-
// wave; the >>2 term makes their slots distinct). Same involution on write
// (via pre-swizzled global src) and read (rule 21).
// ---------------------------------------------------------------------------
__global__ __launch_bounds__(512, 4) void mfma_kernel(const unsigned short* __restrict__ qbf,
                                                      const unsigned short* __restrict__ sbf,
                                                      float* __restrict__ part) {
    // ---- work decode: grid = 1200 1-D blocks ----
    const int xcd = blockIdx.x & 7;
    const int idx = blockIdx.x >> 3;          // 0..149
    const int b   = xcd >> 2;                 // batch (0/1)
    const int mbq = xcd & 3;                  // M quarter
    const int mbsz = (mbq < 3) ? 15 : 14;     // quarter sizes: 15,15,15,14 (=59)
    if (idx >= 10 * mbsz) return;             // block-uniform early exit
    const int g  = idx / (2 * mbsz);
    const int r_ = idx % (2 * mbsz);
    const int nc = r_ / mbsz;
    const int mb = mbq * 15 + (r_ % mbsz);    // 0..58
    const int bg = b * 5 + g;
    const int r0 = mb * MT;
    const int c0 = nc * NT;

    __shared__ __align__(16) char smem[2 * HBUF];          // 48 KB: 2 x (A 8K + B 16K)
    float* Cst = (float*)smem;                             // epilogue [32][CST] = 34.8 KB

    const int t    = threadIdx.x;
    const int lane = t & 63;
    const int wid  = t >> 6;               // 0..7
    const int h    = wid >> 2;             // row half (0/1)
    const int colq = wid & 3;              // col quarter (0..3)

    const unsigned short* qptr = qbf + (size_t)b * MROWS * CN;              // uniform
    const unsigned short* sptr = sbf + (size_t)(b * 25 + g * 5) * HWN * CN; // uniform

    f32x4 acc[4][4];
#pragma unroll
    for (int mt = 0; mt < 4; ++mt)
#pragma unroll
        for (int nt = 0; nt < 4; ++nt)
            acc[mt][nt] = (f32x4)0.f;

    // ---- async staging setup (per-lane source offset, uniform LDS dest) ----
    // One GLDS = 64 lanes x 16B = 1 KB = 16 rows of 64B (32 bf16).
    const int lxr  = lane >> 2;          // 0..15: row within 16-row chunk
    const int lg   = lane & 3;           // dest granule slot (lane-fixed)
    const int gsrc = lg ^ ((lxr ^ (lxr >> 2)) & 3);   // source granule

    // A: wave w stages rows [r0 + w*16, +16) in one chunk
    int ar = r0 + wid * 16 + lxr;            if (ar > MROWS - 1) ar = MROWS - 1;
    const int aoff = ar * CN + gsrc * 8;
    // B: wave w stages cols [c0 + w*32, +32) in two chunks of 16 (clamped)
    int bc0 = c0 + wid * 32 + lxr;           if (bc0 > NSUP - 1) bc0 = NSUP - 1;
    int bc1 = c0 + wid * 32 + 16 + lxr;      if (bc1 > NSUP - 1) bc1 = NSUP - 1;
    const int boff0 = bc0 * CN + gsrc * 8;
    const int boff1 = bc1 * CN + gsrc * 8;

    const int q_ = lane >> 4;      // k-granule (0..3) this lane's MFMA frag needs
    const int lr = lane & 15;      // row/col within 16x16 tile
    const int sl = (q_ ^ ((lr ^ (lr >> 2)) & 3)) * 8;  // read-side swizzled slot (shorts)

    // stage one 24 KB half-tile (A 8K + B 16K) at k-offset kk (shorts)
#define STAGE(base, kk)                                                        \
    {                                                                          \
        char* ad = smem + (base) + wid * 1024;                                 \
        char* bd = smem + (base) + 8192 + wid * 2048;                          \
        GLDS(qptr + aoff  + (kk), ad);                                         \
        GLDS(sptr + boff0 + (kk), bd);                                         \
        GLDS(sptr + boff1 + (kk), bd + 1024);                                  \
    }

    // consume one half-tile: 8 ds_read_b128 + 16 MFMA per wave
#define COMPUTE(base)                                                          \
    {                                                                          \
        const unsigned short* Al = (const unsigned short*)(smem + (base));     \
        const unsigned short* Bl = Al + 4096;                                  \
        bf16x8 af[4];                                                          \
        _Pragma("unroll")                                                      \
        for (int mt = 0; mt < 4; ++mt)                                         \
            af[mt] = *(const bf16x8*)(Al + (h * 64 + mt * 16 + lr) * 32 + sl); \
        _Pragma("unroll")                                                      \
        for (int nt = 0; nt < 4; ++nt) {                                       \
            bf16x8 bfr = *(const bf16x8*)(Bl + (colq * 64 + nt * 16 + lr) * 32 + sl); \
            _Pragma("unroll")                                                  \
            for (int mt = 0; mt < 4; ++mt)                                     \
                acc[mt][nt] = __builtin_amdgcn_mfma_f32_16x16x32_bf16(af[mt], bfr, acc[mt][nt], 0, 0, 0); \
        }                                                                      \
    }

    // ---- pipelined main loop: 20 tiles of BK=32, ping-pong in 48 KB ----
    STAGE(0, 0);                              // tile 0 -> buf0
    __syncthreads();                          // tile 0 landed
#pragma unroll 3
    for (int k2 = 0; k2 < 9; ++k2) {
        const int kk = k2 * 2;
        STAGE(HBUF, (kk + 1) * BK);           // tile kk+1 -> buf1 (flies under compute)
        COMPUTE(0);                           // tile kk
        __syncthreads();                      // vmcnt(0): prefetch landed; buf0 reads done
        STAGE(0, (kk + 2) * BK);              // tile kk+2 -> buf0
        COMPUTE(HBUF);                        // tile kk+1
        __syncthreads();
    }
    STAGE(HBUF, 19 * BK);                     // tile 19 -> buf1
    COMPUTE(0);                               // tile 18
    __syncthreads();
    COMPUTE(HBUF);                            // tile 19
#undef STAGE
#undef COMPUTE

    // -------- epilogue: per-mt, 32 C-rows (both halves) via LDS -----------
    // FULLY UNROLLED over mt (runtime acc[] index -> scratch spill; see R2).
    // Cst (34.8 KB) spans both buffers; the first __syncthreads() below
    // orders it after the last COMPUTE's ds_reads.
    const int erow = t >> 4;        // 0..31 (Cst row)
    const int es   = t & 15;        // 16 scanners per row (within one wave)
#define CE(a, b) { float hi_ = fmaxf(a, b), lo_ = fminf(a, b); a = hi_; b = lo_; }
#pragma unroll
    for (int mt = 0; mt < 4; ++mt) {
        __syncthreads();
#pragma unroll
        for (int nt = 0; nt < 4; ++nt)
#pragma unroll
            for (int e = 0; e < 4; ++e)
                Cst[(h * 16 + q_ * 4 + e) * CST + colq * 64 + nt * 16 + lr] = acc[mt][nt][e];
        __syncthreads();

        float t0 = -3.4e38f, t1 = -3.4e38f, t2 = -3.4e38f, t3 = -3.4e38f, t4 = -3.4e38f;
#pragma unroll
        for (int i = 0; i < 16; ++i) {
            int col = es + 16 * i;
            float v = (c0 + col < NSUP) ? Cst[erow * CST + col] : -3.4e38f;
            float hi;
            hi = fmaxf(t0, v); v = fminf(t0, v); t0 = hi;
            hi = fmaxf(t1, v); v = fminf(t1, v); t1 = hi;
            hi = fmaxf(t2, v); v = fminf(t2, v); t2 = hi;
            hi = fmaxf(t3, v); v = fminf(t3, v); t3 = hi;
            hi = fmaxf(t4, v); v = fminf(t4, v); t4 = hi;
        }
#pragma unroll
        for (int d = 1; d < 16; d <<= 1) {
            float b0 = __shfl_xor(t0, d, 64);
            float b1 = __shfl_xor(t1, d, 64);
            float b2 = __shfl_xor(t2, d, 64);
            float b3 = __shfl_xor(t3, d, 64);
            float b4 = __shfl_xor(t4, d, 64);
            t0 = fmaxf(t0, b4); t1 = fmaxf(t1, b3); t2 = fmaxf(t2, b2);
            t3 = fmaxf(t3, b1); t4 = fmaxf(t4, b0);
            CE(t0, t1); CE(t2, t3);
            CE(t1, t2); CE(t3, t4);
            CE(t0, t1); CE(t2, t3);
            CE(t1, t2); CE(t3, t4);
            CE(t0, t1); CE(t2, t3);
        }
        if (es == 0) {
            // Cst row erow = eh*16 + crow maps to patch r0 + eh*64 + mt*16 + crow
            int patch = r0 + (erow >> 4) * 64 + mt * 16 + (erow & 15);
            if (patch < MROWS) {
                float* pp = part + ((size_t)(bg * MROWS + patch) * 2 + nc) * 5;
                pp[0] = t0; pp[1] = t1; pp[2] = t2; pp[3] = t3; pp[4] = t4;
            }
        }
    }
#undef CE
}

// ---------------------------------------------------------------------------
// Merge: one wave per (b,qi,g) = 750 waves. Top-5 of the union of the two
// sorted per-chunk top-5s, mean, wave-reduce over 100 patches, direct store.
// ---------------------------------------------------------------------------
__global__ __launch_bounds__(256) void merge_kernel(const float* __restrict__ part,
                                                    float* __restrict__ out) {
    int w    = (blockIdx.x * 256 + threadIdx.x) >> 6;
    int lane = threadIdx.x & 63;
    if (w >= 750) return;
    int b  = w / 375, r = w % 375;
    int qi = r / 5,   g = r % 5;
    int bg = b * 5 + g;

    float sum = 0.f;
    for (int p = lane; p < HWN; p += 64) {
        int row = qi * HWN + p;
        const float* pp = part + (size_t)(bg * MROWS + row) * 10;
        float t0 = -3.4e38f, t1 = -3.4e38f, t2 = -3.4e38f, t3 = -3.4e38f, t4 = -3.4e38f;
#pragma unroll
        for (int j = 0; j < 10; ++j) {
            float v = pp[j], hi;
            hi = fmaxf(t0, v); v = fminf(t0, v); t0 = hi;
            hi = fmaxf(t1, v); v = fminf(t1, v); t1 = hi;
            hi = fmaxf(t2, v); v = fminf(t2, v); t2 = hi;
            hi = fmaxf(t3, v); v = fminf(t3, v); t3 = hi;
            hi = fmaxf(t4, v); v = fminf(t4, v); t4 = hi;
        }
        sum += (t0 + t1 + t2 + t3 + t4) * 0.2f;
    }
#pragma unroll
    for (int off = 32; off > 0; off >>= 1)
        sum += __shfl_xor(sum, off, 64);
    if (lane == 0) out[w] = sum;        // out[(b*75+qi)*5+g] == out[w]
}

extern "C" void kernel_launch(void* const* d_in, const int* in_sizes, int n_in,
                              void* d_out, int out_size, void* d_ws, size_t ws_size,
                              hipStream_t stream) {
    const float* in1 = (const float*)d_in[0];
    const float* in2 = (const float*)d_in[1];
    float* out = (float*)d_out;

    unsigned short* qbf  = (unsigned short*)d_ws;            // 15000*640 bf16 = 19.2 MB
    unsigned short* sbf  = qbf + (size_t)NQD * CN;           //  5000*640 bf16 =  6.4 MB
    float*          part = (float*)(sbf + (size_t)NSD * CN); // 750000 fp32 = 3 MB

    prep_kernel<<<dim3(NDESC / 4), 256, 0, stream>>>(in1, in2, qbf, sbf);
    mfma_kernel<<<dim3(1200), 512, 0, stream>>>(qbf, sbf, part);   // XCD-clustered
    merge_kernel<<<dim3(188), 256, 0, stream>>>(part, out);        // 750 waves
}